// Round 17
// baseline (1609.737 us; speedup 1.0000x reference)
//
#include <hip/hip_runtime.h>

// ---------------------------------------------------------------------------
// TLSTM  (B=256, T=256, D=256, H=512)
// Persistent-scan, R16 = in-fragment fused EW (R12, proven-correct) at
// 64-col slices (NO MFMA duplication — R12's mistake) + R13/R15 scheduling.
//   grid = 128 WGs x 256 thr. WG (g,cs): g=bid&15 owns batch rows [g*16,+16),
//   cs=bid>>4 (0..7) owns h-cols [cs*64,+64). Wave nt (0..3) owns the 16-col
//   N-tile cbase+nt*16 and computes ALL 5 GEMMs for it: U-gate B-frags in
//   VGPRs, xproj Win-frags in VGPRs, Wd via LDS. Gate math runs directly on
//   MFMA accumulator fragments (col=lane&15, rows (lane>>4)*4+j) -> no Z
//   tiles, no pre-EW barrier; publish immediately after U-GEMM.
//   Step t: issue x(t+1)+tim(t) -> xproj(t) into frags (X staged at t-1) ->
//   issue h/c (delayed) -> vmcnt(0) -> validate + selective retry (guarded)
//   -> commit h/c -> B1 -> U-GEMM+decomp (accumulate) -> EW in-fragment +
//   tagged publish -> stage X(t+1) -> B2.
//   Exchange: R12's u32 [h|c] with 2-bit tag split across both bf16 LSBs
//   (h LSB at bit16 = tag bit0; c LSB at bit0 = tag bit1), sc0sc1 only.
//   Audits: X writes(post-B1) vs X reads(pre-B1): B1/B2; H/C reads(post-B1,t)
//   vs commit writes(pre-B1,t+1): B2(t); Wd one-time.
// ---------------------------------------------------------------------------

#define T_STEPS 256
#define BATCH   256
#define DIN     256
#define HID     512

typedef __attribute__((ext_vector_type(8))) __bf16 bf16x8;
typedef __attribute__((ext_vector_type(4))) float  f32x4;

#define MFMA(a,b,c) __builtin_amdgcn_mfma_f32_16x16x32_bf16((a),(b),(c),0,0,0)

// LDS layout (byte offsets).
#define H_S     0            // 16 x 1040B
#define C_S     16640        // 16 x 1040B
#define X_S     33280        // 16 x 528B
#define WD_S    41728        // 64 cols x 1040B = 66560
#define LDS_SZ  108288
#define HSTR    1040
#define XSTR    528

struct ScanP {
  const float *x, *tim;
  const float *Wi_w,*Wi_b,*Ui_w,*Ui_b,*bi;
  const float *Wf_w,*Wf_b,*Uf_w,*Uf_b,*bf_;
  const float *Wo_w,*Wo_b,*Uo_w,*Uo_b,*bo;
  const float *Wc_w,*Wc_b,*Uc_w,*Uc_b,*bc;
  const float *Wd_w,*b_dec;
  unsigned int *hc_buf;            // [2][256 rows][512 cols] u32 = [h|c]
  float *h_final;                  // [256][512] fp32
};

__device__ __forceinline__ float fsigm(float z){ return 1.f/(1.f + __expf(-z)); }
__device__ __forceinline__ float ftanh(float z){
  float e = __expf(-2.f*fabsf(z));
  float t = (1.f - e)/(1.f + e);
  return z < 0.f ? -t : t;
}

// device-coherent via MALL (bypass non-coherent L1+L2) — proven path
__device__ __forceinline__ uint4 cld16(const void* p){
  uint4 r;
  asm volatile("global_load_dwordx4 %0, %1, off sc0 sc1"
               : "=v"(r) : "v"(p) : "memory");
  return r;
}
__device__ __forceinline__ void cst4(void* p, unsigned int v){
  asm volatile("global_store_dword %0, %1, off sc0 sc1"
               :: "v"(p), "v"(v) : "memory");
}

__device__ __forceinline__ bf16x8 wfrag8(const float* p){
  const float4* p4 = (const float4*)p;
  float4 a = p4[0], b = p4[1];
  bf16x8 r = { (__bf16)a.x,(__bf16)a.y,(__bf16)a.z,(__bf16)a.w,
               (__bf16)b.x,(__bf16)b.y,(__bf16)b.z,(__bf16)b.w };
  return r;
}

__global__ void __launch_bounds__(256, 1) tlstm_scan(ScanP P)
{
  __shared__ __align__(16) char L[LDS_SZ];
  const int tid  = threadIdx.x;
  const int bid  = blockIdx.x;
  const int g    = bid & 15;         // row group (16 groups x 16 rows)
  const int cs   = bid >> 4;         // col slice (8 slices x 64 cols)
  const int rbase = g * 16;
  const int cbase = cs * 64;
  const int wave = tid >> 6, lane = tid & 63, lo = lane & 15, hi = lane >> 4;
  const int nt   = wave;             // N-tile (16 cols) of this wave

  // ---- one-time: Wd slice (64 cols x 512) fp32 -> bf16 -> LDS [col][K]
  {
    const int col = tid >> 2, seg = tid & 3;          // 128 f32 per (col,seg)
    const float4* src = (const float4*)(P.Wd_w + (size_t)(cbase + col) * HID + seg * 128);
    char* dst = L + WD_S + (size_t)col * 1040 + seg * 256;
#pragma unroll
    for (int j = 0; j < 16; j++){
      float4 a = src[2*j], b = src[2*j+1];
      bf16x8 o = { (__bf16)a.x,(__bf16)a.y,(__bf16)a.z,(__bf16)a.w,
                   (__bf16)b.x,(__bf16)b.y,(__bf16)b.z,(__bf16)b.w };
      *(bf16x8*)(dst + j*16) = o;
    }
  }

  // ---- one-time: B-fragments -> registers (loop-invariant)
  //      U gates: 4 x 16 kc-frags; xproj Win: 4 x 8 q-frags
  bf16x8 bUi[16], bUf[16], bUo[16], bUc[16];
  bf16x8 wXi[8], wXf[8], wXo[8], wXc[8];
  {
    const size_t colbU = (size_t)(cbase + nt * 16 + lo) * HID;
    const size_t colbW = (size_t)(cbase + nt * 16 + lo) * DIN;
#pragma unroll
    for (int kc = 0; kc < 16; kc++){
      bUi[kc] = wfrag8(P.Ui_w + colbU + kc * 32 + hi * 8);
      bUf[kc] = wfrag8(P.Uf_w + colbU + kc * 32 + hi * 8);
      bUo[kc] = wfrag8(P.Uo_w + colbU + kc * 32 + hi * 8);
      bUc[kc] = wfrag8(P.Uc_w + colbU + kc * 32 + hi * 8);
    }
#pragma unroll
    for (int q = 0; q < 8; q++){
      wXi[q] = wfrag8(P.Wi_w + colbW + q * 32 + hi * 8);
      wXf[q] = wfrag8(P.Wf_w + colbW + q * 32 + hi * 8);
      wXo[q] = wfrag8(P.Wo_w + colbW + q * 32 + hi * 8);
      wXc[q] = wfrag8(P.Wc_w + colbW + q * 32 + hi * 8);
    }
  }

  // ---- per-lane elementwise identity: col = colg, rows rb4+0..3
  const int colg = cbase + nt * 16 + (lane & 15);
  const int rb4  = (lane >> 4) * 4;
  float Bi = P.Wi_b[colg] + P.bi[colg]  + P.Ui_b[colg];
  float Bf = P.Wf_b[colg] + P.bf_[colg] + P.Uf_b[colg];
  float Bo = P.Wo_b[colg] + P.bo[colg]  + P.Uo_b[colg];
  float Bc = P.Wc_b[colg] + P.bc[colg]  + P.Uc_b[colg];
  float Bd = P.b_dec[colg];
  f32x4 cr = {0.f, 0.f, 0.f, 0.f};

  const int srow = tid >> 4, sseg = tid & 15;   // x staging map (16x16)

  // ---- prologue: load x(0) (compiler), stage X(0)
  float4 xv[4];
  {
    const float4* xs = (const float4*)(P.x + ((size_t)(rbase + srow) * T_STEPS) * DIN + sseg * 16);
#pragma unroll
    for (int j = 0; j < 4; j++) xv[j] = xs[j];
    char* dst = L + X_S + srow * XSTR + sseg * 32;
#pragma unroll
    for (int j = 0; j < 2; j++){
      float4 a = xv[2*j], b = xv[2*j+1];
      bf16x8 o = { (__bf16)a.x,(__bf16)a.y,(__bf16)a.z,(__bf16)a.w,
                   (__bf16)b.x,(__bf16)b.y,(__bf16)b.z,(__bf16)b.w };
      *(bf16x8*)(dst + j*16) = o;
    }
  }
  __syncthreads();   // Wd + X(0) staged before first use

#pragma unroll 1
  for (int t = 0; t < T_STEPS; ++t){
    const int rp = t & 1;
    const char* hcprevB = (const char*)(P.hc_buf + (size_t)rp * BATCH * HID);
    char* hcnextB = (char*)(P.hc_buf + (size_t)(rp ^ 1) * BATCH * HID);

    // ---- top: issue x(t+1) + tim(t) (compiler loads; drain at validate is
    //      ~coterminal with the h/c MALL RT)
    if (t < T_STEPS - 1){
      const float4* xs = (const float4*)(P.x + ((size_t)(rbase + srow) * T_STEPS + (t + 1)) * DIN + sseg * 16);
#pragma unroll
      for (int j = 0; j < 4; j++) xv[j] = xs[j];
    }
    float tmv[4];
#pragma unroll
    for (int j = 0; j < 4; j++)
      tmv[j] = P.tim[(size_t)(rbase + rb4 + j) * T_STEPS + t];

    // ---- xproj MFMA into register frags (X from t-1 + Win regs);
    //      covers producer publish lag
    f32x4 xi_ = {0.f,0.f,0.f,0.f}, xf_ = xi_, xo_ = xi_, xc_ = xi_;
#pragma unroll
    for (int q = 0; q < 8; q++){
      bf16x8 ax = *(const bf16x8*)(L + X_S + lo * XSTR + q*64 + hi*16);
      xi_ = MFMA(ax, wXi[q], xi_);
      xf_ = MFMA(ax, wXf[q], xf_);
      xo_ = MFMA(ax, wXo[q], xo_);
      xc_ = MFMA(ax, wXc[q], xc_);
    }

    // ---- issue h/c loads (delayed: producers likely published)
    uint4 gr[8];
    const char* src = hcprevB + (size_t)(rbase + wave * 4) * 2048;
#pragma unroll
    for (int j = 0; j < 8; j++){
      int row = j >> 1;                       // within this wave's 4 rows
      int Lg  = (j & 1) * 64 + lane;          // 16B granule within row
      gr[j] = cld16(src + (size_t)row * 2048 + (size_t)Lg * 16);
    }
    asm volatile("s_waitcnt vmcnt(0)" ::: "memory");
    __builtin_amdgcn_sched_barrier(0);

    // ---- validate tags; selective retry (guarded). u32 = [h|c]: tag bit0
    //      at bit16 (h LSB), tag bit1 at bit0 (c LSB).
    {
      const unsigned int expv = ((unsigned int)(t & 1) << 16)
                              |  (unsigned int)((t >> 1) & 1);
      unsigned int stale = 0;
#pragma unroll
      for (int j = 0; j < 8; j++){
        unsigned int bad = ((gr[j].x ^ expv) | (gr[j].y ^ expv)
                          | (gr[j].z ^ expv) | (gr[j].w ^ expv)) & 0x00010001u;
        stale |= (bad ? 1u : 0u) << j;
      }
      int guard = 0;
      while (__any((int)stale) && ++guard < 65536){
#pragma unroll
        for (int j = 0; j < 8; j++){
          if (stale & (1u << j)){
            int row = j >> 1;
            int Lg  = (j & 1) * 64 + lane;
            gr[j] = cld16(src + (size_t)row * 2048 + (size_t)Lg * 16);
          }
        }
        asm volatile("s_waitcnt vmcnt(0)" ::: "memory");
        __builtin_amdgcn_sched_barrier(0);
        unsigned int ns = 0;
#pragma unroll
        for (int j = 0; j < 8; j++){
          if (stale & (1u << j)){
            unsigned int bad = ((gr[j].x ^ expv) | (gr[j].y ^ expv)
                              | (gr[j].z ^ expv) | (gr[j].w ^ expv)) & 0x00010001u;
            ns |= (bad ? 1u : 0u) << j;
          }
        }
        stale = ns;
      }
    }

    // ---- commit h/c to LDS (unpack [h|c] u32 quads -> bf16 rows)
    {
#pragma unroll
      for (int j = 0; j < 8; j++){
        int row = wave * 4 + (j >> 1);
        int Lg  = (j & 1) * 64 + lane;
        uint2 hp = { (gr[j].x >> 16) | (gr[j].y & 0xffff0000u),
                     (gr[j].z >> 16) | (gr[j].w & 0xffff0000u) };
        uint2 cp = { (gr[j].x & 0xffffu) | (gr[j].y << 16),
                     (gr[j].z & 0xffffu) | (gr[j].w << 16) };
        *(uint2*)(L + H_S + row * HSTR + Lg * 8) = hp;
        *(uint2*)(L + C_S + row * HSTR + Lg * 8) = cp;
      }
    }
    __syncthreads();   // B1: H/C committed (all waves past xproj X reads)

    // ---- U-GEMM + decomp MFMA (this wave's 16 cols; no duplication)
    f32x4 zi_ = {0.f,0.f,0.f,0.f}, zf_ = zi_, zo_ = zi_, zc_ = zi_, zd_ = zi_;
#pragma unroll
    for (int kc = 0; kc < 16; kc++){
      bf16x8 a = *(const bf16x8*)(L + H_S + lo * HSTR + kc*64 + hi*16);
      zi_ = MFMA(a, bUi[kc], zi_);
      zf_ = MFMA(a, bUf[kc], zf_);
      zo_ = MFMA(a, bUo[kc], zo_);
      zc_ = MFMA(a, bUc[kc], zc_);
    }
#pragma unroll
    for (int kc = 0; kc < 16; kc++){
      bf16x8 a  = *(const bf16x8*)(L + C_S + lo * HSTR + kc*64 + hi*16);
      bf16x8 wd = *(const bf16x8*)(L + WD_S + (size_t)(nt*16 + lo) * 1040 + kc*64 + hi*16);
      zd_ = MFMA(a, wd, zd_);
    }

    // ---- elementwise IN-FRAGMENT; publish tagged u32 immediately
    {
      const unsigned int e0n = (unsigned int)((t + 1) & 1);
      const unsigned int e1n = (unsigned int)(((t + 1) >> 1) & 1);
#pragma unroll
      for (int j = 0; j < 4; j++){
        float zi = zi_[j] + xi_[j] + Bi;
        float zf = zf_[j] + xf_[j] + Bf;
        float zo = zo_[j] + xo_[j] + Bo;
        float zc = zc_[j] + xc_[j] + Bc;
        float zdv = zd_[j] + Bd;
        float Tmap = 1.f / __logf(tmv[j] + 2.7183f);
        float cst = ftanh(zdv);
        float c1  = cr[j] - cst + Tmap * cst;
        float ig = fsigm(zi), fg = fsigm(zf), og = fsigm(zo);
        float ch = ftanh(zc);
        float c2 = fg * c1 + ig * ch;
        float hv = og * ftanh(c2);
        cr[j] = c2;
        if (t < T_STEPS - 1){
          unsigned int hb = (unsigned int)__builtin_bit_cast(unsigned short, (__bf16)hv);
          unsigned int cb = (unsigned int)__builtin_bit_cast(unsigned short, (__bf16)c2);
          unsigned int w = (((hb & 0xFFFEu) | e0n) << 16)
                         |  ((cb & 0xFFFEu) | e1n);
          cst4(hcnextB + (size_t)(rbase + rb4 + j) * 2048 + (size_t)colg * 4, w);
        } else {
          P.h_final[(size_t)(rbase + rb4 + j) * HID + colg] = hv;
        }
      }
    }

    // ---- stage X(t+1) (hides behind peers' EW/publish)
    if (t < T_STEPS - 1){
      char* dst = L + X_S + srow * XSTR + sseg * 32;
#pragma unroll
      for (int j = 0; j < 2; j++){
        float4 a = xv[2*j], b = xv[2*j+1];
        bf16x8 o = { (__bf16)a.x,(__bf16)a.y,(__bf16)a.z,(__bf16)a.w,
                     (__bf16)b.x,(__bf16)b.y,(__bf16)b.z,(__bf16)b.w };
        *(bf16x8*)(dst + j*16) = o;
      }
    }
    __syncthreads();   // B2: X(t+1) staged; H/C reads done before commit(t+1)
  }
}

// ---------------- head: out = relu(hT @ fc_w^T + fc_b) @ cls_w^T + cls_b ----
__global__ void __launch_bounds__(256) tlstm_head(const float* __restrict__ hfin,
    const float* __restrict__ fc_w, const float* __restrict__ fc_b,
    const float* __restrict__ cls_w, const float* __restrict__ cls_b,
    float* __restrict__ out)
{
  __shared__ float hrow[512];
  __shared__ float fcv[256];
  const int b = blockIdx.x, tid = threadIdx.x;
  ((float2*)hrow)[tid] = ((const float2*)(hfin + (size_t)b * 512))[tid];
  __syncthreads();
  {
    const float4* w4 = (const float4*)(fc_w + (size_t)tid * 512);
    const float4* h4 = (const float4*)hrow;
    float acc = fc_b[tid];
#pragma unroll 4
    for (int k = 0; k < 128; k++){
      float4 w = w4[k], h = h4[k];
      acc += w.x*h.x + w.y*h.y + w.z*h.z + w.w*h.w;
    }
    fcv[tid] = fmaxf(acc, 0.f);
  }
  __syncthreads();
  const int wave = tid >> 6, lane = tid & 63;
  if (wave < 2){
    const float* cw = cls_w + wave * 256;
    float s = 0.f;
#pragma unroll
    for (int j = lane; j < 256; j += 64) s += fcv[j] * cw[j];
#pragma unroll
    for (int off = 32; off > 0; off >>= 1) s += __shfl_down(s, off, 64);
    if (lane == 0) out[b * 2 + wave] = s + cls_b[wave];
  }
}

// ---------------------------------------------------------------------------
extern "C" void kernel_launch(void* const* d_in, const int* in_sizes, int n_in,
                              void* d_out, int out_size, void* d_ws, size_t ws_size,
                              hipStream_t stream)
{
  (void)in_sizes; (void)n_in; (void)out_size; (void)ws_size;

  ScanP P;
  P.x    = (const float*)d_in[0];
  P.tim  = (const float*)d_in[1];
  P.Wi_w = (const float*)d_in[2];  P.Wi_b = (const float*)d_in[3];
  P.Ui_w = (const float*)d_in[4];  P.Ui_b = (const float*)d_in[5];  P.bi  = (const float*)d_in[6];
  P.Wf_w = (const float*)d_in[7];  P.Wf_b = (const float*)d_in[8];
  P.Uf_w = (const float*)d_in[9];  P.Uf_b = (const float*)d_in[10]; P.bf_ = (const float*)d_in[11];
  P.Wo_w = (const float*)d_in[12]; P.Wo_b = (const float*)d_in[13];
  P.Uo_w = (const float*)d_in[14]; P.Uo_b = (const float*)d_in[15]; P.bo  = (const float*)d_in[16];
  P.Wc_w = (const float*)d_in[17]; P.Wc_b = (const float*)d_in[18];
  P.Uc_w = (const float*)d_in[19]; P.Uc_b = (const float*)d_in[20]; P.bc  = (const float*)d_in[21];
  P.Wd_w = (const float*)d_in[22]; P.b_dec = (const float*)d_in[23];
  const float* fc_w  = (const float*)d_in[24];
  const float* fc_b  = (const float*)d_in[25];
  const float* cls_w = (const float*)d_in[26];
  const float* cls_b = (const float*)d_in[27];

  // workspace layout: [hc_buf 2x512K u32][h_final 512K]
  unsigned int* hc_buf = (unsigned int*)d_ws;                    // 2*256*512 u32
  float* h_final = (float*)(hc_buf + 2 * BATCH * HID);           // 256*512 f32
  P.hc_buf = hc_buf; P.h_final = h_final;

  // zero hc (tag bits 0 == tag of t=-1; payload h=c=0)
  hipMemsetAsync(d_ws, 0, (size_t)2 * BATCH * HID * 4, stream);

  hipLaunchKernelGGL(tlstm_scan, dim3(128), dim3(256), 0, stream, P);
  hipLaunchKernelGGL(tlstm_head, dim3(256), dim3(256), 0, stream,
                     h_final, fc_w, fc_b, cls_w, cls_b, (float*)d_out);
}

// Round 18
// 1271.261 us; speedup vs baseline: 1.2663x; 1.2663x over previous
//
#include <hip/hip_runtime.h>

// ---------------------------------------------------------------------------
// TLSTM  (B=256, T=256, D=256, H=512)
// R17 = two-cohort interleaved persistent scan.
//   grid = 256 WGs x 256 thr (1 WG/CU). WG: pair p=bid&7 owns row-groups
//   gA=p (rows p*16..), gB=p+8 (rows p*16+128..); cs=bid>>3 owns 16 cols.
//   Cohorts A,B are independent recurrences; schedule interleaves them so
//   each cohort's exchange RT + peer skew hides under the other's compute.
//   Per cohort per wave: U-GEMM gate=wave (16 MFMA, frags in VGPR), decomp
//   kc-quarter (4 MFMA, partial tiles summed in EW), xproj gate=wave
//   (8 MFMA, Win frags in VGPR). EW: 1 element/thread/cohort.
//   Exchange: tagged u32 [h|c] (R12/R16-proven): tag bit0 -> h LSB (bit16),
//   tag bit1 -> c LSB (bit0); sc0sc1; validate + selective retry (guarded).
//   Barriers are RAW s_barrier + lgkmcnt(0) (LDS ordering only) so in-flight
//   VMEM crosses them (HIP __syncthreads would drain vmcnt and expose RT).
//   All barrier paths are wave-uniform.
// ---------------------------------------------------------------------------

#define T_STEPS 256
#define BATCH   256
#define DIN     256
#define HID     512

typedef __attribute__((ext_vector_type(8))) __bf16 bf16x8;
typedef __attribute__((ext_vector_type(4))) float  f32x4;

#define MFMA(a,b,c) __builtin_amdgcn_mfma_f32_16x16x32_bf16((a),(b),(c),0,0,0)

// LDS layout (byte offsets).
#define HA_S    0            // 16 x 1040B
#define CA_S    16640
#define HB_S    33280
#define CB_S    49920
#define XA_S    66560        // 16 x 528B
#define XB_S    75008
#define Z_S     83456        // 32 tiles x 16x17 f32 (A:0..15, B:16..31)
#define LDS_SZ  118272
#define HSTR    1040
#define XSTR    528
#define ZROW    17
// per-cohort tile ids (+0 for A, +16 for B):
//   U gate g = g (0..3); dec partial w = 4+w (4..7);
//   xproj gate g parity par = 8 + par*4 + g (8..15)

struct ScanP {
  const float *x, *tim;
  const float *Wi_w,*Wi_b,*Ui_w,*Ui_b,*bi;
  const float *Wf_w,*Wf_b,*Uf_w,*Uf_b,*bf_;
  const float *Wo_w,*Wo_b,*Uo_w,*Uo_b,*bo;
  const float *Wc_w,*Wc_b,*Uc_w,*Uc_b,*bc;
  const float *Wd_w,*b_dec;
  unsigned int *hc_buf;            // [2][256 rows][512 cols] u32 = [h|c]
  float *h_final;                  // [256][512] fp32
};

__device__ __forceinline__ float fsigm(float z){ return 1.f/(1.f + __expf(-z)); }
__device__ __forceinline__ float ftanh(float z){
  float e = __expf(-2.f*fabsf(z));
  float t = (1.f - e)/(1.f + e);
  return z < 0.f ? -t : t;
}

// device-coherent via MALL (bypass non-coherent L1+L2) — proven path
__device__ __forceinline__ uint4 cld16(const void* p){
  uint4 r;
  asm volatile("global_load_dwordx4 %0, %1, off sc0 sc1"
               : "=v"(r) : "v"(p) : "memory");
  return r;
}
__device__ __forceinline__ void cst4(void* p, unsigned int v){
  asm volatile("global_store_dword %0, %1, off sc0 sc1"
               :: "v"(p), "v"(v) : "memory");
}
// raw barrier: orders LDS only; in-flight VMEM crosses (intentional)
__device__ __forceinline__ void lbar(){
  asm volatile("s_waitcnt lgkmcnt(0)" ::: "memory");
  __builtin_amdgcn_s_barrier();
}

__device__ __forceinline__ bf16x8 wfrag8(const float* p){
  const float4* p4 = (const float4*)p;
  float4 a = p4[0], b = p4[1];
  bf16x8 r = { (__bf16)a.x,(__bf16)a.y,(__bf16)a.z,(__bf16)a.w,
               (__bf16)b.x,(__bf16)b.y,(__bf16)b.z,(__bf16)b.w };
  return r;
}
__device__ __forceinline__ void zstore(char* L, int tile, int lane, f32x4 v){
  float* p = (float*)(L + Z_S) + tile*(16*ZROW) + ((lane>>4)*4)*ZROW + (lane&15);
  p[0]=v[0]; p[ZROW]=v[1]; p[2*ZROW]=v[2]; p[3*ZROW]=v[3];
}
__device__ __forceinline__ float zread(const char* L, int tile, int r, int c){
  return ((const float*)(L + Z_S))[tile*(16*ZROW) + r*ZROW + c];
}

__device__ __forceinline__ void issue_hc(uint4* gr, const char* src, int lane){
#pragma unroll
  for (int j = 0; j < 8; j++){
    int row = j >> 1;
    int Lg  = (j & 1) * 64 + lane;
    gr[j] = cld16(src + (size_t)row * 2048 + (size_t)Lg * 16);
  }
}
__device__ __forceinline__ void validate_retry(uint4* gr, const char* src,
                                               int lane, unsigned int expv){
  unsigned int stale = 0;
#pragma unroll
  for (int j = 0; j < 8; j++){
    unsigned int bad = ((gr[j].x ^ expv) | (gr[j].y ^ expv)
                      | (gr[j].z ^ expv) | (gr[j].w ^ expv)) & 0x00010001u;
    stale |= (bad ? 1u : 0u) << j;
  }
  int guard = 0;
  while (__any((int)stale) && ++guard < 65536){
#pragma unroll
    for (int j = 0; j < 8; j++){
      if (stale & (1u << j)){
        int row = j >> 1;
        int Lg  = (j & 1) * 64 + lane;
        gr[j] = cld16(src + (size_t)row * 2048 + (size_t)Lg * 16);
      }
    }
    asm volatile("s_waitcnt vmcnt(0)" ::: "memory");
    __builtin_amdgcn_sched_barrier(0);
    unsigned int ns = 0;
#pragma unroll
    for (int j = 0; j < 8; j++){
      if (stale & (1u << j)){
        unsigned int bad = ((gr[j].x ^ expv) | (gr[j].y ^ expv)
                          | (gr[j].z ^ expv) | (gr[j].w ^ expv)) & 0x00010001u;
        ns |= (bad ? 1u : 0u) << j;
      }
    }
    stale = ns;
  }
}
__device__ __forceinline__ void commit_hc(char* L, int Hs, int Cs,
                                          const uint4* gr, int wave, int lane){
#pragma unroll
  for (int j = 0; j < 8; j++){
    int row = wave * 4 + (j >> 1);
    int Lg  = (j & 1) * 64 + lane;
    uint2 hp = { (gr[j].x >> 16) | (gr[j].y & 0xffff0000u),
                 (gr[j].z >> 16) | (gr[j].w & 0xffff0000u) };
    uint2 cp = { (gr[j].x & 0xffffu) | (gr[j].y << 16),
                 (gr[j].z & 0xffffu) | (gr[j].w << 16) };
    *(uint2*)(L + Hs + row * HSTR + Lg * 8) = hp;
    *(uint2*)(L + Cs + row * HSTR + Lg * 8) = cp;
  }
}
__device__ __forceinline__ void stageX(char* L, int Xs, int srow, int sseg,
                                       const float4* xv){
  char* dst = L + Xs + srow * XSTR + sseg * 32;
#pragma unroll
  for (int j = 0; j < 2; j++){
    float4 a = xv[2*j], b = xv[2*j+1];
    bf16x8 o = { (__bf16)a.x,(__bf16)a.y,(__bf16)a.z,(__bf16)a.w,
                 (__bf16)b.x,(__bf16)b.y,(__bf16)b.z,(__bf16)b.w };
    *(bf16x8*)(dst + j*16) = o;
  }
}

__global__ void __launch_bounds__(256, 1) tlstm_scan(ScanP P)
{
  __shared__ __align__(16) char L[LDS_SZ];
  const int tid  = threadIdx.x;
  const int bid  = blockIdx.x;
  const int p    = bid & 7;          // group pair
  const int cs   = bid >> 3;         // 0..31 col slice (16 cols)
  const int rbA  = p * 16;
  const int rbB  = rbA + 128;
  const int cbase = cs * 16;
  const int wave = tid >> 6, lane = tid & 63, lo = lane & 15, hi = lane >> 4;

  // ---- one-time: B-fragments in VGPRs (this wave's gate + dec quarter)
  bf16x8 bU[16], wX[8], bWd[4];
  {
    const float* Uw = (wave == 0) ? P.Ui_w : (wave == 1) ? P.Uf_w
                    : (wave == 2) ? P.Uo_w : P.Uc_w;
    const float* Ww = (wave == 0) ? P.Wi_w : (wave == 1) ? P.Wf_w
                    : (wave == 2) ? P.Wo_w : P.Wc_w;
    const size_t cU = (size_t)(cbase + lo) * HID;
    const size_t cW = (size_t)(cbase + lo) * DIN;
#pragma unroll
    for (int kc = 0; kc < 16; kc++) bU[kc] = wfrag8(Uw + cU + kc * 32 + hi * 8);
#pragma unroll
    for (int q = 0; q < 8; q++)     wX[q]  = wfrag8(Ww + cW + q * 32 + hi * 8);
#pragma unroll
    for (int kq = 0; kq < 4; kq++)
      bWd[kq] = wfrag8(P.Wd_w + cU + (wave * 4 + kq) * 32 + hi * 8);
  }

  // ---- per-thread EW identity: row r (0..15), col c (0..15), per cohort
  const int er = tid >> 4, ec = tid & 15;
  const int colg = cbase + ec;
  float Bi = P.Wi_b[colg] + P.bi[colg]  + P.Ui_b[colg];
  float Bf = P.Wf_b[colg] + P.bf_[colg] + P.Uf_b[colg];
  float Bo = P.Wo_b[colg] + P.bo[colg]  + P.Uo_b[colg];
  float Bc = P.Wc_b[colg] + P.bc[colg]  + P.Uc_b[colg];
  float Bd = P.b_dec[colg];
  float crA = 0.f, crB = 0.f;

  const int srow = tid >> 4, sseg = tid & 15;   // x staging map (16x16)

  // ---- prologue: stage XA(0), XB(0); xproj(0) both; issue A(0); xv(1)s
  float4 xvA[4], xvB[4];
  {
    const float4* xa = (const float4*)(P.x + ((size_t)(rbA + srow) * T_STEPS) * DIN + sseg * 16);
    const float4* xb = (const float4*)(P.x + ((size_t)(rbB + srow) * T_STEPS) * DIN + sseg * 16);
#pragma unroll
    for (int j = 0; j < 4; j++){ xvA[j] = xa[j]; xvB[j] = xb[j]; }
    stageX(L, XA_S, srow, sseg, xvA);
    stageX(L, XB_S, srow, sseg, xvB);
  }
  __syncthreads();
  {
    f32x4 xa = {0.f,0.f,0.f,0.f}, xb = xa;
#pragma unroll
    for (int q = 0; q < 8; q++){
      bf16x8 a0 = *(const bf16x8*)(L + XA_S + lo * XSTR + q*64 + hi*16);
      bf16x8 b0 = *(const bf16x8*)(L + XB_S + lo * XSTR + q*64 + hi*16);
      xa = MFMA(a0, wX[q], xa);
      xb = MFMA(b0, wX[q], xb);
    }
    zstore(L,  0 + 8 + 0 + wave, lane, xa);   // Z2A par0
    zstore(L, 16 + 8 + 0 + wave, lane, xb);   // Z2B par0
  }
  uint4 grA[8], grB[8];
  issue_hc(grA, (const char*)P.hc_buf + (size_t)(rbA + wave * 4) * 2048, lane);
  {
    const float4* xa = (const float4*)(P.x + ((size_t)(rbA + srow) * T_STEPS + 1) * DIN + sseg * 16);
    const float4* xb = (const float4*)(P.x + ((size_t)(rbB + srow) * T_STEPS + 1) * DIN + sseg * 16);
#pragma unroll
    for (int j = 0; j < 4; j++){ xvA[j] = xa[j]; xvB[j] = xb[j]; }
  }

#pragma unroll 1
  for (int t = 0; t < T_STEPS; ++t){
    const int rp  = t & 1;
    const int par = t & 1, parn = (t + 1) & 1;
    const char* hcprev = (const char*)(P.hc_buf + (size_t)rp * BATCH * HID);
    char* hcnext = (char*)(P.hc_buf + (size_t)(rp ^ 1) * BATCH * HID);
    const unsigned int expv = ((unsigned int)(t & 1) << 16)
                            |  (unsigned int)((t >> 1) & 1);
    const unsigned int e0n = (unsigned int)((t + 1) & 1);
    const unsigned int e1n = (unsigned int)(((t + 1) >> 1) & 1);

    // ===================== cohort A =====================
    asm volatile("s_waitcnt vmcnt(0)" ::: "memory");
    __builtin_amdgcn_sched_barrier(0);
    validate_retry(grA, hcprev + (size_t)(rbA + wave * 4) * 2048, lane, expv);
    commit_hc(L, HA_S, CA_S, grA, wave, lane);
    // issue B(t) h/c loads — fly across A's compute (raw barriers don't drain)
    issue_hc(grB, hcprev + (size_t)(rbB + wave * 4) * 2048, lane);
    lbar();                                   // B1a: H/C-A committed

    {   // U-GEMM A (gate=wave) + dec partial; stage XA(t+1)
      f32x4 zU = {0.f,0.f,0.f,0.f}, zD = zU;
#pragma unroll
      for (int kc = 0; kc < 16; kc++){
        bf16x8 a = *(const bf16x8*)(L + HA_S + lo * HSTR + kc*64 + hi*16);
        zU = MFMA(a, bU[kc], zU);
      }
#pragma unroll
      for (int kq = 0; kq < 4; kq++){
        bf16x8 a = *(const bf16x8*)(L + CA_S + lo * HSTR + (wave*4+kq)*64 + hi*16);
        zD = MFMA(a, bWd[kq], zD);
      }
      zstore(L, 0 + wave, lane, zU);
      zstore(L, 4 + wave, lane, zD);
      if (t + 1 < T_STEPS) stageX(L, XA_S, srow, sseg, xvA);
    }
    lbar();                                   // B2a: Z-A ready, XA(t+1) staged

    {   // EW A + publish A(t)
      float tv = P.tim[(size_t)(rbA + er) * T_STEPS + t];
      float Tmap = 1.f / __logf(tv + 2.7183f);
      float zi = zread(L, 0, er, ec) + zread(L, 8+par*4+0, er, ec) + Bi;
      float zf = zread(L, 1, er, ec) + zread(L, 8+par*4+1, er, ec) + Bf;
      float zo = zread(L, 2, er, ec) + zread(L, 8+par*4+2, er, ec) + Bo;
      float zc = zread(L, 3, er, ec) + zread(L, 8+par*4+3, er, ec) + Bc;
      float zdv = zread(L, 4, er, ec) + zread(L, 5, er, ec)
                + zread(L, 6, er, ec) + zread(L, 7, er, ec) + Bd;
      float cst = ftanh(zdv);
      float c1  = crA - cst + Tmap * cst;
      float ig = fsigm(zi), fg = fsigm(zf), og = fsigm(zo);
      float ch = ftanh(zc);
      float c2 = fg * c1 + ig * ch;
      float hv = og * ftanh(c2);
      crA = c2;
      if (t < T_STEPS - 1){
        unsigned int hb = (unsigned int)__builtin_bit_cast(unsigned short, (__bf16)hv);
        unsigned int cb = (unsigned int)__builtin_bit_cast(unsigned short, (__bf16)c2);
        unsigned int w = (((hb & 0xFFFEu) | e0n) << 16) | ((cb & 0xFFFEu) | e1n);
        cst4(hcnext + (size_t)(rbA + er) * 2048 + (size_t)colg * 4, w);
      } else {
        P.h_final[(size_t)(rbA + er) * HID + colg] = hv;
      }
    }

    if (t + 1 < T_STEPS){   // xprojA(t+1) -> Z2A[parn] (XA(t+1) post-B2a)
      f32x4 xa = {0.f,0.f,0.f,0.f};
#pragma unroll
      for (int q = 0; q < 8; q++){
        bf16x8 a0 = *(const bf16x8*)(L + XA_S + lo * XSTR + q*64 + hi*16);
        xa = MFMA(a0, wX[q], xa);
      }
      zstore(L, 8 + parn*4 + wave, lane, xa);
    }

    // ===================== cohort B =====================
    asm volatile("s_waitcnt vmcnt(0)" ::: "memory");
    __builtin_amdgcn_sched_barrier(0);
    validate_retry(grB, hcprev + (size_t)(rbB + wave * 4) * 2048, lane, expv);
    commit_hc(L, HB_S, CB_S, grB, wave, lane);
    // issue A(t+1) h/c + x(t+2) prefetches — fly across B's compute
    if (t + 1 < T_STEPS)
      issue_hc(grA, (const char*)(P.hc_buf + (size_t)((rp^1)) * BATCH * HID)
                    + (size_t)(rbA + wave * 4) * 2048, lane);
    if (t + 2 < T_STEPS){
      const float4* xa = (const float4*)(P.x + ((size_t)(rbA + srow) * T_STEPS + (t + 2)) * DIN + sseg * 16);
#pragma unroll
      for (int j = 0; j < 4; j++) xvA[j] = xa[j];
    }
    lbar();                                   // B1b: H/C-B committed

    {   // U-GEMM B + dec partial; stage XB(t+1)
      f32x4 zU = {0.f,0.f,0.f,0.f}, zD = zU;
#pragma unroll
      for (int kc = 0; kc < 16; kc++){
        bf16x8 a = *(const bf16x8*)(L + HB_S + lo * HSTR + kc*64 + hi*16);
        zU = MFMA(a, bU[kc], zU);
      }
#pragma unroll
      for (int kq = 0; kq < 4; kq++){
        bf16x8 a = *(const bf16x8*)(L + CB_S + lo * HSTR + (wave*4+kq)*64 + hi*16);
        zD = MFMA(a, bWd[kq], zD);
      }
      zstore(L, 16 + wave, lane, zU);
      zstore(L, 20 + wave, lane, zD);
      if (t + 1 < T_STEPS) stageX(L, XB_S, srow, sseg, xvB);
    }
    lbar();                                   // B2b: Z-B ready, XB(t+1) staged

    {   // EW B + publish B(t)
      float tv = P.tim[(size_t)(rbB + er) * T_STEPS + t];
      float Tmap = 1.f / __logf(tv + 2.7183f);
      float zi = zread(L, 16, er, ec) + zread(L, 24+par*4+0, er, ec) + Bi;
      float zf = zread(L, 17, er, ec) + zread(L, 24+par*4+1, er, ec) + Bf;
      float zo = zread(L, 18, er, ec) + zread(L, 24+par*4+2, er, ec) + Bo;
      float zc = zread(L, 19, er, ec) + zread(L, 24+par*4+3, er, ec) + Bc;
      float zdv = zread(L, 20, er, ec) + zread(L, 21, er, ec)
                + zread(L, 22, er, ec) + zread(L, 23, er, ec) + Bd;
      float cst = ftanh(zdv);
      float c1  = crB - cst + Tmap * cst;
      float ig = fsigm(zi), fg = fsigm(zf), og = fsigm(zo);
      float ch = ftanh(zc);
      float c2 = fg * c1 + ig * ch;
      float hv = og * ftanh(c2);
      crB = c2;
      if (t < T_STEPS - 1){
        unsigned int hb = (unsigned int)__builtin_bit_cast(unsigned short, (__bf16)hv);
        unsigned int cb = (unsigned int)__builtin_bit_cast(unsigned short, (__bf16)c2);
        unsigned int w = (((hb & 0xFFFEu) | e0n) << 16) | ((cb & 0xFFFEu) | e1n);
        cst4(hcnext + (size_t)(rbB + er) * 2048 + (size_t)colg * 4, w);
      } else {
        P.h_final[(size_t)(rbB + er) * HID + colg] = hv;
      }
    }

    if (t + 1 < T_STEPS){   // xprojB(t+1) -> Z2B[parn]; prefetch xvB(t+2)
      f32x4 xb = {0.f,0.f,0.f,0.f};
#pragma unroll
      for (int q = 0; q < 8; q++){
        bf16x8 b0 = *(const bf16x8*)(L + XB_S + lo * XSTR + q*64 + hi*16);
        xb = MFMA(b0, wX[q], xb);
      }
      zstore(L, 16 + 8 + parn*4 + wave, lane, xb);
      if (t + 2 < T_STEPS){
        const float4* xbp = (const float4*)(P.x + ((size_t)(rbB + srow) * T_STEPS + (t + 2)) * DIN + sseg * 16);
#pragma unroll
        for (int j = 0; j < 4; j++) xvB[j] = xbp[j];
      }
    }
  }
}

// ---------------- head: out = relu(hT @ fc_w^T + fc_b) @ cls_w^T + cls_b ----
__global__ void __launch_bounds__(256) tlstm_head(const float* __restrict__ hfin,
    const float* __restrict__ fc_w, const float* __restrict__ fc_b,
    const float* __restrict__ cls_w, const float* __restrict__ cls_b,
    float* __restrict__ out)
{
  __shared__ float hrow[512];
  __shared__ float fcv[256];
  const int b = blockIdx.x, tid = threadIdx.x;
  ((float2*)hrow)[tid] = ((const float2*)(hfin + (size_t)b * 512))[tid];
  __syncthreads();
  {
    const float4* w4 = (const float4*)(fc_w + (size_t)tid * 512);
    const float4* h4 = (const float4*)hrow;
    float acc = fc_b[tid];
#pragma unroll 4
    for (int k = 0; k < 128; k++){
      float4 w = w4[k], h = h4[k];
      acc += w.x*h.x + w.y*h.y + w.z*h.z + w.w*h.w;
    }
    fcv[tid] = fmaxf(acc, 0.f);
  }
  __syncthreads();
  const int wave = tid >> 6, lane = tid & 63;
  if (wave < 2){
    const float* cw = cls_w + wave * 256;
    float s = 0.f;
#pragma unroll
    for (int j = lane; j < 256; j += 64) s += fcv[j] * cw[j];
#pragma unroll
    for (int off = 32; off > 0; off >>= 1) s += __shfl_down(s, off, 64);
    if (lane == 0) out[b * 2 + wave] = s + cls_b[wave];
  }
}

// ---------------------------------------------------------------------------
extern "C" void kernel_launch(void* const* d_in, const int* in_sizes, int n_in,
                              void* d_out, int out_size, void* d_ws, size_t ws_size,
                              hipStream_t stream)
{
  (void)in_sizes; (void)n_in; (void)out_size; (void)ws_size;

  ScanP P;
  P.x    = (const float*)d_in[0];
  P.tim  = (const float*)d_in[1];
  P.Wi_w = (const float*)d_in[2];  P.Wi_b = (const float*)d_in[3];
  P.Ui_w = (const float*)d_in[4];  P.Ui_b = (const float*)d_in[5];  P.bi  = (const float*)d_in[6];
  P.Wf_w = (const float*)d_in[7];  P.Wf_b = (const float*)d_in[8];
  P.Uf_w = (const float*)d_in[9];  P.Uf_b = (const float*)d_in[10]; P.bf_ = (const float*)d_in[11];
  P.Wo_w = (const float*)d_in[12]; P.Wo_b = (const float*)d_in[13];
  P.Uo_w = (const float*)d_in[14]; P.Uo_b = (const float*)d_in[15]; P.bo  = (const float*)d_in[16];
  P.Wc_w = (const float*)d_in[17]; P.Wc_b = (const float*)d_in[18];
  P.Uc_w = (const float*)d_in[19]; P.Uc_b = (const float*)d_in[20]; P.bc  = (const float*)d_in[21];
  P.Wd_w = (const float*)d_in[22]; P.b_dec = (const float*)d_in[23];
  const float* fc_w  = (const float*)d_in[24];
  const float* fc_b  = (const float*)d_in[25];
  const float* cls_w = (const float*)d_in[26];
  const float* cls_b = (const float*)d_in[27];

  // workspace layout: [hc_buf 2x512K u32][h_final 512K]
  unsigned int* hc_buf = (unsigned int*)d_ws;                    // 2*256*512 u32
  float* h_final = (float*)(hc_buf + 2 * BATCH * HID);           // 256*512 f32
  P.hc_buf = hc_buf; P.h_final = h_final;

  // zero hc (tag bits 0 == tag of t=-1; payload h=c=0)
  hipMemsetAsync(d_ws, 0, (size_t)2 * BATCH * HID * 4, stream);

  hipLaunchKernelGGL(tlstm_scan, dim3(256), dim3(256), 0, stream, P);
  hipLaunchKernelGGL(tlstm_head, dim3(256), dim3(256), 0, stream,
                     h_final, fc_w, fc_b, cls_w, cls_b, (float*)d_out);
}

// Round 19
// 985.743 us; speedup vs baseline: 1.6330x; 1.2896x over previous
//
#include <hip/hip_runtime.h>

// ---------------------------------------------------------------------------
// TLSTM  (B=256, T=256, D=256, H=512)
// Persistent-scan, R18 = R15 (proven, 869us) + ONE delta: h/c issue point
// moved to the MIDDLE of xproj (after gate g0's 8 MFMA, before g1's).
//   R13 proved delaying the issue past xproj wins when producers publish
//   late (stale-common). The loop is now 20% faster, so the optimal issue
//   point may be earlier: half-xproj overlap of the MALL RT, snapshot only
//   ~0.1us earlier. Bounded A/B: stale steps cost at most one retry RT.
//   Everything else (Z2 parity dbuf, 2 raw-less barriers, tagged u64
//   exchange, selective retry, delayed-vs-R11 ordering) is R15 verbatim.
// ---------------------------------------------------------------------------

#define T_STEPS 256
#define BATCH   256
#define DIN     256
#define HID     512

typedef __attribute__((ext_vector_type(8))) __bf16 bf16x8;
typedef __attribute__((ext_vector_type(4))) float  f32x4;

#define MFMA(a,b,c) __builtin_amdgcn_mfma_f32_16x16x32_bf16((a),(b),(c),0,0,0)

// LDS layout (byte offsets).
#define H_S     0            // 16 x 1040B
#define C_S     16640        // 16 x 1040B
#define X_S     33280        // 16 x 528B
#define WIN_S   41728        // 4 gates x 32 cols x 528B = 67584
#define Z_S     109312       // 10 tiles x 16x17 f32 = 10880 (U 0..7, dec 8,9)
#define Z2_S    120192       // 2 parity x 8 tiles x 16x17 f32 = 17408 (xproj)
#define LDS_SZ  137600
#define HSTR    1040
#define XSTR    528
#define ZROW    17
// Z tile ids: U gate g at N-tile nt = g*2+nt (0..7); decomp = 8+nt.
// Z2 tile ids (per parity): xproj gate g at nt = g*2+nt (0..7).

struct ScanP {
  const float *x, *tim;
  const float *Wi_w,*Wi_b,*Ui_w,*Ui_b,*bi;
  const float *Wf_w,*Wf_b,*Uf_w,*Uf_b,*bf_;
  const float *Wo_w,*Wo_b,*Uo_w,*Uo_b,*bo;
  const float *Wc_w,*Wc_b,*Uc_w,*Uc_b,*bc;
  const float *Wd_w,*b_dec;
  unsigned long long *hc_buf;      // [2][256 rows][256 col-pairs] u64
  float *h_final;                  // [256][512] fp32
  unsigned int *flags;             // kept in ws layout; unused
};

__device__ __forceinline__ float fsigm(float z){ return 1.f/(1.f + __expf(-z)); }
__device__ __forceinline__ float ftanh(float z){
  float e = __expf(-2.f*fabsf(z));
  float t = (1.f - e)/(1.f + e);
  return z < 0.f ? -t : t;
}

// device-coherent via MALL (bypass non-coherent L1+L2) — R3..R15 proven path
__device__ __forceinline__ uint4 cld16(const void* p){
  uint4 r;
  asm volatile("global_load_dwordx4 %0, %1, off sc0 sc1"
               : "=v"(r) : "v"(p) : "memory");
  return r;
}
__device__ __forceinline__ void cst8(void* p, unsigned long long v){
  asm volatile("global_store_dwordx2 %0, %1, off sc0 sc1"
               :: "v"(p), "v"(v) : "memory");
}

__device__ __forceinline__ bf16x8 wfrag8(const float* p){
  const float4* p4 = (const float4*)p;
  float4 a = p4[0], b = p4[1];
  bf16x8 r = { (__bf16)a.x,(__bf16)a.y,(__bf16)a.z,(__bf16)a.w,
               (__bf16)b.x,(__bf16)b.y,(__bf16)b.z,(__bf16)b.w };
  return r;
}
__device__ __forceinline__ void zstore(char* L, int tile, int lane, f32x4 v){
  float* p = (float*)(L + Z_S) + tile*(16*ZROW) + ((lane>>4)*4)*ZROW + (lane&15);
  p[0]=v[0]; p[ZROW]=v[1]; p[2*ZROW]=v[2]; p[3*ZROW]=v[3];
}
__device__ __forceinline__ float zread(const char* L, int tile, int r, int c){
  return ((const float*)(L + Z_S))[tile*(16*ZROW) + r*ZROW + c];
}
__device__ __forceinline__ void z2store(char* L, int par, int tile, int lane, f32x4 v){
  float* p = (float*)(L + Z2_S) + (par*8 + tile)*(16*ZROW) + ((lane>>4)*4)*ZROW + (lane&15);
  p[0]=v[0]; p[ZROW]=v[1]; p[2*ZROW]=v[2]; p[3*ZROW]=v[3];
}
__device__ __forceinline__ float z2read(const char* L, int par, int tile, int r, int c){
  return ((const float*)(L + Z2_S))[(par*8 + tile)*(16*ZROW) + r*ZROW + c];
}

__global__ void __launch_bounds__(256, 1) tlstm_scan(ScanP P)
{
  __shared__ __align__(16) char L[LDS_SZ];
  const int tid  = threadIdx.x;
  const int bid  = blockIdx.x;
  const int g    = bid & 15;         // row group (16 groups x 16 rows)
  const int cs   = bid >> 4;         // col slice (16 slices x 32 cols)
  const int rbase = g * 16;
  const int cbase = cs * 32;
  const int wave = tid >> 6, lane = tid & 63, lo = lane & 15, hi = lane >> 4;
  const int nt   = wave & 1;         // N-tile within the 32-col slice
  const int gp   = wave >> 1;        // gate pair: 0 -> {i,f}, 1 -> {o,c}
  const int g0   = gp * 2, g1 = g0 + 1;

  // ---- one-time: Win slices (4 gates x 32 cols x 256) fp32 -> bf16 -> LDS
  {
    const float* Wg = (wave == 0) ? P.Wi_w : (wave == 1) ? P.Wf_w
                    : (wave == 2) ? P.Wo_w : P.Wc_w;
    const int wc = lane >> 1, q2 = lane & 1;
    const float4* src = (const float4*)(Wg + (size_t)(cbase + wc) * DIN + q2 * 128);
    char* dst = L + WIN_S + (size_t)(wave * 32 + wc) * XSTR + q2 * 256;
#pragma unroll
    for (int j = 0; j < 16; j++){
      float4 a = src[2*j], b = src[2*j+1];
      bf16x8 o = { (__bf16)a.x,(__bf16)a.y,(__bf16)a.z,(__bf16)a.w,
                   (__bf16)b.x,(__bf16)b.y,(__bf16)b.z,(__bf16)b.w };
      *(bf16x8*)(dst + j*16) = o;
    }
  }

  // ---- one-time: U/Wd B-fragments -> registers (loop-invariant)
  bf16x8 bP[16], bQ[16], bR[16];
  {
    const float* Pw = (gp == 0) ? P.Ui_w : P.Uo_w;
    const float* Qw = (gp == 0) ? P.Uf_w : P.Uc_w;
    const size_t colb = (size_t)(cbase + nt * 16 + lo) * HID;
#pragma unroll
    for (int kc = 0; kc < 16; kc++){
      bP[kc] = wfrag8(Pw + colb + kc * 32 + hi * 8);
      bQ[kc] = wfrag8(Qw + colb + kc * 32 + hi * 8);
    }
    if (wave >= 2){
#pragma unroll
      for (int kc = 0; kc < 16; kc++)
        bR[kc] = wfrag8(P.Wd_w + colb + kc * 32 + hi * 8);
    }
  }

  // ---- per-thread elementwise ownership: erow=tid>>4, cols cbase+(tid&15)*2
  const int erow = tid >> 4;
  const int ecp  = (tid & 15) * 2;
  float bias_i[2], bias_f[2], bias_o[2], bias_c[2], bias_d[2], cr[2];
#pragma unroll
  for (int e = 0; e < 2; e++){
    int c = cbase + ecp + e;
    bias_i[e] = P.Wi_b[c] + P.bi[c]  + P.Ui_b[c];
    bias_f[e] = P.Wf_b[c] + P.bf_[c] + P.Uf_b[c];
    bias_o[e] = P.Wo_b[c] + P.bo[c]  + P.Uo_b[c];
    bias_c[e] = P.Wc_b[c] + P.bc[c]  + P.Uc_b[c];
    bias_d[e] = P.b_dec[c];
    cr[e] = 0.f;
  }

  const int srow = tid >> 4, sseg = tid & 15;   // x staging map (16x16)
  const size_t pub_off = ((size_t)(rbase + erow) * 256 + cs * 16 + (tid & 15)) * 8;

  // ---- prologue: load x(0) (compiler), stage X(0); barrier covers Win too
  float4 xv[4];
  {
    const float4* xs = (const float4*)(P.x + ((size_t)(rbase + srow) * T_STEPS) * DIN + sseg * 16);
#pragma unroll
    for (int j = 0; j < 4; j++) xv[j] = xs[j];
    char* dst = L + X_S + srow * XSTR + sseg * 32;
#pragma unroll
    for (int j = 0; j < 2; j++){
      float4 a = xv[2*j], b = xv[2*j+1];
      bf16x8 o = { (__bf16)a.x,(__bf16)a.y,(__bf16)a.z,(__bf16)a.w,
                   (__bf16)b.x,(__bf16)b.y,(__bf16)b.z,(__bf16)b.w };
      *(bf16x8*)(dst + j*16) = o;
    }
  }
  __syncthreads();   // Win + X(0) staged before first use

#pragma unroll 1
  for (int t = 0; t < T_STEPS; ++t){
    const int rp = t & 1;
    const int p2 = t & 1;
    const char* hcprev = (const char*)(P.hc_buf + (size_t)rp * BATCH * 256);
    char* hcnext = (char*)(P.hc_buf + (size_t)(rp ^ 1) * BATCH * 256);

    // ---- top: issue x(t+1) + tim(t) (compiler loads; drain at validate is
    //      ~coterminal with the h/c MALL RT -> no added stall)
    if (t < T_STEPS - 1){
      const float4* xs = (const float4*)(P.x + ((size_t)(rbase + srow) * T_STEPS + (t + 1)) * DIN + sseg * 16);
#pragma unroll
      for (int j = 0; j < 4; j++) xv[j] = xs[j];
    }
    const float tv = P.tim[(size_t)(rbase + erow) * T_STEPS + t];

    // ---- xproj gate g0 (X from step t-1 + Win)
    f32x4 xA = {0.f,0.f,0.f,0.f}, xB = xA;
#pragma unroll
    for (int q = 0; q < 8; q++){
      bf16x8 ax = *(const bf16x8*)(L + X_S + lo * XSTR + q*64 + hi*16);
      bf16x8 w0 = *(const bf16x8*)(L + WIN_S + (size_t)(g0*32 + nt*16 + lo) * XSTR + q*64 + hi*16);
      xA = MFMA(ax, w0, xA);
    }

    // ---- issue h/c loads at the xproj midpoint (R18 delta: RT overlaps
    //      gate g1's MFMA; snapshot ~0.1us earlier than R15)
    uint4 gr[8];
    const char* src = hcprev + (size_t)(rbase + wave * 4) * 2048;
#pragma unroll
    for (int j = 0; j < 8; j++){
      int row = j >> 1;                       // within this wave's 4 rows
      int gg  = (j & 1) * 64 + lane;          // 16B granule within row
      gr[j] = cld16(src + (size_t)row * 2048 + (size_t)gg * 16);
    }
    __builtin_amdgcn_sched_barrier(0);        // pin issue before g1 MFMAs

    // ---- xproj gate g1 (covers the h/c flight)
#pragma unroll
    for (int q = 0; q < 8; q++){
      bf16x8 ax = *(const bf16x8*)(L + X_S + lo * XSTR + q*64 + hi*16);
      bf16x8 w1 = *(const bf16x8*)(L + WIN_S + (size_t)(g1*32 + nt*16 + lo) * XSTR + q*64 + hi*16);
      xB = MFMA(ax, w1, xB);
    }
    z2store(L, p2, g0*2+nt, lane, xA);
    z2store(L, p2, g1*2+nt, lane, xB);

    asm volatile("s_waitcnt vmcnt(0)" ::: "memory");
    __builtin_amdgcn_sched_barrier(0);

    // ---- validate tags; selective retry (R8/R9/R13 verbatim, 8 entries)
    {
      const unsigned int expv = (unsigned int)(t & 1)
                              | ((unsigned int)((t >> 1) & 1) << 16);
      unsigned int stale = 0;
#pragma unroll
      for (int j = 0; j < 8; j++){
        unsigned int bad = ((gr[j].x ^ expv) | (gr[j].y ^ expv)
                          | (gr[j].z ^ expv) | (gr[j].w ^ expv)) & 0x00010001u;
        stale |= (bad ? 1u : 0u) << j;
      }
      int guard = 0;
      while (__any((int)stale) && ++guard < 65536){
#pragma unroll
        for (int j = 0; j < 8; j++){
          if (stale & (1u << j)){
            int row = j >> 1;
            int gg  = (j & 1) * 64 + lane;
            gr[j] = cld16(src + (size_t)row * 2048 + (size_t)gg * 16);
          }
        }
        asm volatile("s_waitcnt vmcnt(0)" ::: "memory");
        __builtin_amdgcn_sched_barrier(0);
        unsigned int ns = 0;
#pragma unroll
        for (int j = 0; j < 8; j++){
          if (stale & (1u << j)){
            unsigned int bad = ((gr[j].x ^ expv) | (gr[j].y ^ expv)
                              | (gr[j].z ^ expv) | (gr[j].w ^ expv)) & 0x00010001u;
            ns |= (bad ? 1u : 0u) << j;
          }
        }
        stale = ns;
      }
    }

    // ---- commit h/c to LDS. gr = [h01,c01,h23,c23] -> h {x,z}, c {y,w}
    {
#pragma unroll
      for (int j = 0; j < 8; j++){
        int row = wave * 4 + (j >> 1);
        int gg  = (j & 1) * 64 + lane;
        *(uint2*)(L + H_S + row * HSTR + gg * 8) = uint2{gr[j].x, gr[j].z};
        *(uint2*)(L + C_S + row * HSTR + gg * 8) = uint2{gr[j].y, gr[j].w};
      }
    }
    __syncthreads();   // B1: H/C committed (all waves past xproj reads of X)

    // ---- U-GEMM + decomp MFMA (Z 0..9); then stage X(t+1) (hides in MFMA)
    {
      f32x4 zA = {0.f,0.f,0.f,0.f}, zB = zA, zD = zA;
#pragma unroll
      for (int kc = 0; kc < 16; kc++){
        bf16x8 a = *(const bf16x8*)(L + H_S + lo * HSTR + kc*64 + hi*16);
        zA = MFMA(a, bP[kc], zA);
        zB = MFMA(a, bQ[kc], zB);
      }
      if (wave >= 2){
#pragma unroll
        for (int kc = 0; kc < 16; kc++){
          bf16x8 a = *(const bf16x8*)(L + C_S + lo * HSTR + kc*64 + hi*16);
          zD = MFMA(a, bR[kc], zD);
        }
      }
      zstore(L, g0*2+nt, lane, zA);
      zstore(L, g1*2+nt, lane, zB);
      if (wave >= 2) zstore(L, 8+nt, lane, zD);
    }
    if (t < T_STEPS - 1){
      char* dst = L + X_S + srow * XSTR + sseg * 32;
#pragma unroll
      for (int j = 0; j < 2; j++){
        float4 a = xv[2*j], b = xv[2*j+1];
        bf16x8 o = { (__bf16)a.x,(__bf16)a.y,(__bf16)a.z,(__bf16)a.w,
                     (__bf16)b.x,(__bf16)b.y,(__bf16)b.z,(__bf16)b.w };
        *(bf16x8*)(dst + j*16) = o;
      }
    }
    __syncthreads();   // B2: Z ready + X(t+1) staged

    // ---- elementwise gate math (fp32); publish tagged u64
    {
      float Tmap = 1.f / __logf(tv + 2.7183f);
      unsigned int hpk = 0, cpk = 0;
      float hv2[2];
#pragma unroll
      for (int e = 0; e < 2; e++){
        int col = ecp + e;
        int ntc = col >> 4, cl = col & 15;
        float zi = zread(L, 0+ntc,  erow, cl) + z2read(L, p2, 0+ntc, erow, cl) + bias_i[e];
        float zf = zread(L, 2+ntc,  erow, cl) + z2read(L, p2, 2+ntc, erow, cl) + bias_f[e];
        float zo = zread(L, 4+ntc,  erow, cl) + z2read(L, p2, 4+ntc, erow, cl) + bias_o[e];
        float zc = zread(L, 6+ntc,  erow, cl) + z2read(L, p2, 6+ntc, erow, cl) + bias_c[e];
        float zdv = zread(L, 8+ntc, erow, cl) + bias_d[e];
        float cst = ftanh(zdv);
        float c1  = cr[e] - cst + Tmap * cst;
        float ig = fsigm(zi), fg = fsigm(zf), og = fsigm(zo);
        float ch = ftanh(zc);
        float c2 = fg * c1 + ig * ch;
        float hv_ = og * ftanh(c2);
        cr[e] = c2; hv2[e] = hv_;
        hpk |= (unsigned int)__builtin_bit_cast(unsigned short, (__bf16)hv_) << (16*e);
        cpk |= (unsigned int)__builtin_bit_cast(unsigned short, (__bf16)c2) << (16*e);
      }
      if (t < T_STEPS - 1){
        const unsigned int wtag  = (unsigned int)((t + 1) & 3);
        const unsigned int tmask = (wtag & 1u) | ((wtag >> 1) << 16);
        hpk = (hpk & 0xFFFEFFFEu) | tmask;   // full tag in both bf16 LSBs
        cpk = (cpk & 0xFFFEFFFEu) | tmask;
        cst8(hcnext + pub_off,
             (unsigned long long)hpk | ((unsigned long long)cpk << 32));
      } else {
        size_t off = (size_t)(rbase + erow) * HID + cbase + ecp;
        P.h_final[off]     = hv2[0];
        P.h_final[off + 1] = hv2[1];
      }
    }
    // no tail barrier: next step's Z2 writes use opposite parity; next step's
    // commit (H/C writes) is after B1-crossing of all waves; X writes at
    // t+1's UGEMM phase are after B1(t+1). EW(t) reads are all pre-B1(t+1).
  }
}

// ---------------- head: out = relu(hT @ fc_w^T + fc_b) @ cls_w^T + cls_b ----
__global__ void __launch_bounds__(256) tlstm_head(const float* __restrict__ hfin,
    const float* __restrict__ fc_w, const float* __restrict__ fc_b,
    const float* __restrict__ cls_w, const float* __restrict__ cls_b,
    float* __restrict__ out)
{
  __shared__ float hrow[512];
  __shared__ float fcv[256];
  const int b = blockIdx.x, tid = threadIdx.x;
  ((float2*)hrow)[tid] = ((const float2*)(hfin + (size_t)b * 512))[tid];
  __syncthreads();
  {
    const float4* w4 = (const float4*)(fc_w + (size_t)tid * 512);
    const float4* h4 = (const float4*)hrow;
    float acc = fc_b[tid];
#pragma unroll 4
    for (int k = 0; k < 128; k++){
      float4 w = w4[k], h = h4[k];
      acc += w.x*h.x + w.y*h.y + w.z*h.z + w.w*h.w;
    }
    fcv[tid] = fmaxf(acc, 0.f);
  }
  __syncthreads();
  const int wave = tid >> 6, lane = tid & 63;
  if (wave < 2){
    const float* cw = cls_w + wave * 256;
    float s = 0.f;
#pragma unroll
    for (int j = lane; j < 256; j += 64) s += fcv[j] * cw[j];
#pragma unroll
    for (int off = 32; off > 0; off >>= 1) s += __shfl_down(s, off, 64);
    if (lane == 0) out[b * 2 + wave] = s + cls_b[wave];
  }
}

// ---------------------------------------------------------------------------
extern "C" void kernel_launch(void* const* d_in, const int* in_sizes, int n_in,
                              void* d_out, int out_size, void* d_ws, size_t ws_size,
                              hipStream_t stream)
{
  (void)in_sizes; (void)n_in; (void)out_size; (void)ws_size;

  ScanP P;
  P.x    = (const float*)d_in[0];
  P.tim  = (const float*)d_in[1];
  P.Wi_w = (const float*)d_in[2];  P.Wi_b = (const float*)d_in[3];
  P.Ui_w = (const float*)d_in[4];  P.Ui_b = (const float*)d_in[5];  P.bi  = (const float*)d_in[6];
  P.Wf_w = (const float*)d_in[7];  P.Wf_b = (const float*)d_in[8];
  P.Uf_w = (const float*)d_in[9];  P.Uf_b = (const float*)d_in[10]; P.bf_ = (const float*)d_in[11];
  P.Wo_w = (const float*)d_in[12]; P.Wo_b = (const float*)d_in[13];
  P.Uo_w = (const float*)d_in[14]; P.Uo_b = (const float*)d_in[15]; P.bo  = (const float*)d_in[16];
  P.Wc_w = (const float*)d_in[17]; P.Wc_b = (const float*)d_in[18];
  P.Uc_w = (const float*)d_in[19]; P.Uc_b = (const float*)d_in[20]; P.bc  = (const float*)d_in[21];
  P.Wd_w = (const float*)d_in[22]; P.b_dec = (const float*)d_in[23];
  const float* fc_w  = (const float*)d_in[24];
  const float* fc_b  = (const float*)d_in[25];
  const float* cls_w = (const float*)d_in[26];
  const float* cls_b = (const float*)d_in[27];

  // workspace layout (identical to R3..R15): [hc_buf 1M][flags 1K][h_final 512K]
  unsigned long long* hc_buf = (unsigned long long*)d_ws;        // 2*256*256 u64
  unsigned int* flags = (unsigned int*)(hc_buf + 2 * BATCH * 256);
  float* h_final = (float*)((char*)flags + 1024);                // 256*512 f32
  P.hc_buf = hc_buf; P.h_final = h_final; P.flags = flags;

  const size_t zero_bytes = (size_t)2 * BATCH * 256 * 8 + 1024;  // hc + flags
  hipMemsetAsync(d_ws, 0, zero_bytes, stream);

  hipLaunchKernelGGL(tlstm_scan, dim3(256), dim3(256), 0, stream, P);
  hipLaunchKernelGGL(tlstm_head, dim3(256), dim3(256), 0, stream,
                     h_final, fc_w, fc_b, cls_w, cls_b, (float*)d_out);
}

// Round 20
// 869.625 us; speedup vs baseline: 1.8511x; 1.1335x over previous
//
#include <hip/hip_runtime.h>

// ---------------------------------------------------------------------------
// TLSTM  (B=256, T=256, D=256, H=512)
// FINAL = R15 (best proven: 869us, 10x over baseline).
// Persistent-scan: grid = 256 WGs x 256 thr (1 WG/CU). WG (g,cs): g=bid&15
// owns batch rows [g*16,+16), cs=bid>>4 owns h-cols [cs*32,+32).
//   Step t: issue x(t+1)+tim(t) -> xproj(t) [X staged at t-1] -> Z2[t&1]
//   (parity dbuf) -> issue h/c (delayed; stale-common-optimal point, R13/R18
//   A/B) -> vmcnt(0) -> tag-validate + selective retry (guarded) -> commit
//   h/c -> B1 -> U-GEMM+decomp (Z0-9) + stage X(t+1) -> B2 -> EW + tagged
//   publish. 2 barriers/step.
//   Exchange: self-validating tagged u64 [h0,h1|c0,c1] per col-pair; 2-bit
//   step tag w(t)=(t+1)&3 in the LSBs of all four bf16 (each dword
//   independently tear-proof); sc0sc1 (MALL, bypass non-coherent L1/L2).
//   No flags, no fences, producers never wait; retry guarded (no-hang).
//   Session-falsified alternatives: consumer-side wait-fill (R8,R11 null),
//   fused in-fragment EW (R12,R16 regress), cohort interleave (R17 regress),
//   same-XCD L2 exchange (R4,R5,R14 unsound under graph replay), earlier
//   h/c issue (R18 regress). Remaining 3.4us/step = ~1.2us compute chain +
//   ~2.1us fabric RT + 16-peer skew (latency floor of this decomposition;
//   not a HW roofline: MfmaUtil 10.7%, HBM 3.5%).
// ---------------------------------------------------------------------------

#define T_STEPS 256
#define BATCH   256
#define DIN     256
#define HID     512

typedef __attribute__((ext_vector_type(8))) __bf16 bf16x8;
typedef __attribute__((ext_vector_type(4))) float  f32x4;

#define MFMA(a,b,c) __builtin_amdgcn_mfma_f32_16x16x32_bf16((a),(b),(c),0,0,0)

// LDS layout (byte offsets).
#define H_S     0            // 16 x 1040B
#define C_S     16640        // 16 x 1040B
#define X_S     33280        // 16 x 528B
#define WIN_S   41728        // 4 gates x 32 cols x 528B = 67584
#define Z_S     109312       // 10 tiles x 16x17 f32 = 10880 (U 0..7, dec 8,9)
#define Z2_S    120192       // 2 parity x 8 tiles x 16x17 f32 = 17408 (xproj)
#define LDS_SZ  137600
#define HSTR    1040
#define XSTR    528
#define ZROW    17
// Z tile ids: U gate g at N-tile nt = g*2+nt (0..7); decomp = 8+nt.
// Z2 tile ids (per parity): xproj gate g at nt = g*2+nt (0..7).

struct ScanP {
  const float *x, *tim;
  const float *Wi_w,*Wi_b,*Ui_w,*Ui_b,*bi;
  const float *Wf_w,*Wf_b,*Uf_w,*Uf_b,*bf_;
  const float *Wo_w,*Wo_b,*Uo_w,*Uo_b,*bo;
  const float *Wc_w,*Wc_b,*Uc_w,*Uc_b,*bc;
  const float *Wd_w,*b_dec;
  unsigned long long *hc_buf;      // [2][256 rows][256 col-pairs] u64
  float *h_final;                  // [256][512] fp32
  unsigned int *flags;             // kept in ws layout; unused
};

__device__ __forceinline__ float fsigm(float z){ return 1.f/(1.f + __expf(-z)); }
__device__ __forceinline__ float ftanh(float z){
  float e = __expf(-2.f*fabsf(z));
  float t = (1.f - e)/(1.f + e);
  return z < 0.f ? -t : t;
}

// device-coherent via MALL (bypass non-coherent L1+L2) — R3..R15 proven path
__device__ __forceinline__ uint4 cld16(const void* p){
  uint4 r;
  asm volatile("global_load_dwordx4 %0, %1, off sc0 sc1"
               : "=v"(r) : "v"(p) : "memory");
  return r;
}
__device__ __forceinline__ void cst8(void* p, unsigned long long v){
  asm volatile("global_store_dwordx2 %0, %1, off sc0 sc1"
               :: "v"(p), "v"(v) : "memory");
}

__device__ __forceinline__ bf16x8 wfrag8(const float* p){
  const float4* p4 = (const float4*)p;
  float4 a = p4[0], b = p4[1];
  bf16x8 r = { (__bf16)a.x,(__bf16)a.y,(__bf16)a.z,(__bf16)a.w,
               (__bf16)b.x,(__bf16)b.y,(__bf16)b.z,(__bf16)b.w };
  return r;
}
__device__ __forceinline__ void zstore(char* L, int tile, int lane, f32x4 v){
  float* p = (float*)(L + Z_S) + tile*(16*ZROW) + ((lane>>4)*4)*ZROW + (lane&15);
  p[0]=v[0]; p[ZROW]=v[1]; p[2*ZROW]=v[2]; p[3*ZROW]=v[3];
}
__device__ __forceinline__ float zread(const char* L, int tile, int r, int c){
  return ((const float*)(L + Z_S))[tile*(16*ZROW) + r*ZROW + c];
}
__device__ __forceinline__ void z2store(char* L, int par, int tile, int lane, f32x4 v){
  float* p = (float*)(L + Z2_S) + (par*8 + tile)*(16*ZROW) + ((lane>>4)*4)*ZROW + (lane&15);
  p[0]=v[0]; p[ZROW]=v[1]; p[2*ZROW]=v[2]; p[3*ZROW]=v[3];
}
__device__ __forceinline__ float z2read(const char* L, int par, int tile, int r, int c){
  return ((const float*)(L + Z2_S))[(par*8 + tile)*(16*ZROW) + r*ZROW + c];
}

__global__ void __launch_bounds__(256, 1) tlstm_scan(ScanP P)
{
  __shared__ __align__(16) char L[LDS_SZ];
  const int tid  = threadIdx.x;
  const int bid  = blockIdx.x;
  const int g    = bid & 15;         // row group (16 groups x 16 rows)
  const int cs   = bid >> 4;         // col slice (16 slices x 32 cols)
  const int rbase = g * 16;
  const int cbase = cs * 32;
  const int wave = tid >> 6, lane = tid & 63, lo = lane & 15, hi = lane >> 4;
  const int nt   = wave & 1;         // N-tile within the 32-col slice
  const int gp   = wave >> 1;        // gate pair: 0 -> {i,f}, 1 -> {o,c}
  const int g0   = gp * 2, g1 = g0 + 1;

  // ---- one-time: Win slices (4 gates x 32 cols x 256) fp32 -> bf16 -> LDS
  {
    const float* Wg = (wave == 0) ? P.Wi_w : (wave == 1) ? P.Wf_w
                    : (wave == 2) ? P.Wo_w : P.Wc_w;
    const int wc = lane >> 1, q2 = lane & 1;
    const float4* src = (const float4*)(Wg + (size_t)(cbase + wc) * DIN + q2 * 128);
    char* dst = L + WIN_S + (size_t)(wave * 32 + wc) * XSTR + q2 * 256;
#pragma unroll
    for (int j = 0; j < 16; j++){
      float4 a = src[2*j], b = src[2*j+1];
      bf16x8 o = { (__bf16)a.x,(__bf16)a.y,(__bf16)a.z,(__bf16)a.w,
                   (__bf16)b.x,(__bf16)b.y,(__bf16)b.z,(__bf16)b.w };
      *(bf16x8*)(dst + j*16) = o;
    }
  }

  // ---- one-time: U/Wd B-fragments -> registers (loop-invariant)
  bf16x8 bP[16], bQ[16], bR[16];
  {
    const float* Pw = (gp == 0) ? P.Ui_w : P.Uo_w;
    const float* Qw = (gp == 0) ? P.Uf_w : P.Uc_w;
    const size_t colb = (size_t)(cbase + nt * 16 + lo) * HID;
#pragma unroll
    for (int kc = 0; kc < 16; kc++){
      bP[kc] = wfrag8(Pw + colb + kc * 32 + hi * 8);
      bQ[kc] = wfrag8(Qw + colb + kc * 32 + hi * 8);
    }
    if (wave >= 2){
#pragma unroll
      for (int kc = 0; kc < 16; kc++)
        bR[kc] = wfrag8(P.Wd_w + colb + kc * 32 + hi * 8);
    }
  }

  // ---- per-thread elementwise ownership: erow=tid>>4, cols cbase+(tid&15)*2
  const int erow = tid >> 4;
  const int ecp  = (tid & 15) * 2;
  float bias_i[2], bias_f[2], bias_o[2], bias_c[2], bias_d[2], cr[2];
#pragma unroll
  for (int e = 0; e < 2; e++){
    int c = cbase + ecp + e;
    bias_i[e] = P.Wi_b[c] + P.bi[c]  + P.Ui_b[c];
    bias_f[e] = P.Wf_b[c] + P.bf_[c] + P.Uf_b[c];
    bias_o[e] = P.Wo_b[c] + P.bo[c]  + P.Uo_b[c];
    bias_c[e] = P.Wc_b[c] + P.bc[c]  + P.Uc_b[c];
    bias_d[e] = P.b_dec[c];
    cr[e] = 0.f;
  }

  const int srow = tid >> 4, sseg = tid & 15;   // x staging map (16x16)
  const size_t pub_off = ((size_t)(rbase + erow) * 256 + cs * 16 + (tid & 15)) * 8;

  // ---- prologue: load x(0) (compiler), stage X(0); barrier covers Win too
  float4 xv[4];
  {
    const float4* xs = (const float4*)(P.x + ((size_t)(rbase + srow) * T_STEPS) * DIN + sseg * 16);
#pragma unroll
    for (int j = 0; j < 4; j++) xv[j] = xs[j];
    char* dst = L + X_S + srow * XSTR + sseg * 32;
#pragma unroll
    for (int j = 0; j < 2; j++){
      float4 a = xv[2*j], b = xv[2*j+1];
      bf16x8 o = { (__bf16)a.x,(__bf16)a.y,(__bf16)a.z,(__bf16)a.w,
                   (__bf16)b.x,(__bf16)b.y,(__bf16)b.z,(__bf16)b.w };
      *(bf16x8*)(dst + j*16) = o;
    }
  }
  __syncthreads();   // Win + X(0) staged before first use

#pragma unroll 1
  for (int t = 0; t < T_STEPS; ++t){
    const int rp = t & 1;
    const int p2 = t & 1;
    const char* hcprev = (const char*)(P.hc_buf + (size_t)rp * BATCH * 256);
    char* hcnext = (char*)(P.hc_buf + (size_t)(rp ^ 1) * BATCH * 256);

    // ---- top: issue x(t+1) + tim(t) (compiler loads; drain at validate is
    //      ~coterminal with the h/c MALL RT -> no added stall)
    if (t < T_STEPS - 1){
      const float4* xs = (const float4*)(P.x + ((size_t)(rbase + srow) * T_STEPS + (t + 1)) * DIN + sseg * 16);
#pragma unroll
      for (int j = 0; j < 4; j++) xv[j] = xs[j];
    }
    const float tv = P.tim[(size_t)(rbase + erow) * T_STEPS + t];

    // ---- xproj MFMA (X from step t-1 + Win) -> Z2[t&1]; covers publish lag
    f32x4 xA = {0.f,0.f,0.f,0.f}, xB = xA;
#pragma unroll
    for (int q = 0; q < 8; q++){
      bf16x8 ax = *(const bf16x8*)(L + X_S + lo * XSTR + q*64 + hi*16);
      bf16x8 w0 = *(const bf16x8*)(L + WIN_S + (size_t)(g0*32 + nt*16 + lo) * XSTR + q*64 + hi*16);
      bf16x8 w1 = *(const bf16x8*)(L + WIN_S + (size_t)(g1*32 + nt*16 + lo) * XSTR + q*64 + hi*16);
      xA = MFMA(ax, w0, xA);
      xB = MFMA(ax, w1, xB);
    }
    z2store(L, p2, g0*2+nt, lane, xA);
    z2store(L, p2, g1*2+nt, lane, xB);

    // ---- issue h/c loads (delayed: producers likely published)
    uint4 gr[8];
    const char* src = hcprev + (size_t)(rbase + wave * 4) * 2048;
#pragma unroll
    for (int j = 0; j < 8; j++){
      int row = j >> 1;                       // within this wave's 4 rows
      int gg  = (j & 1) * 64 + lane;          // 16B granule within row
      gr[j] = cld16(src + (size_t)row * 2048 + (size_t)gg * 16);
    }
    asm volatile("s_waitcnt vmcnt(0)" ::: "memory");
    __builtin_amdgcn_sched_barrier(0);

    // ---- validate tags; selective retry (R8/R9/R13 verbatim, 8 entries)
    {
      const unsigned int expv = (unsigned int)(t & 1)
                              | ((unsigned int)((t >> 1) & 1) << 16);
      unsigned int stale = 0;
#pragma unroll
      for (int j = 0; j < 8; j++){
        unsigned int bad = ((gr[j].x ^ expv) | (gr[j].y ^ expv)
                          | (gr[j].z ^ expv) | (gr[j].w ^ expv)) & 0x00010001u;
        stale |= (bad ? 1u : 0u) << j;
      }
      int guard = 0;
      while (__any((int)stale) && ++guard < 65536){
#pragma unroll
        for (int j = 0; j < 8; j++){
          if (stale & (1u << j)){
            int row = j >> 1;
            int gg  = (j & 1) * 64 + lane;
            gr[j] = cld16(src + (size_t)row * 2048 + (size_t)gg * 16);
          }
        }
        asm volatile("s_waitcnt vmcnt(0)" ::: "memory");
        __builtin_amdgcn_sched_barrier(0);
        unsigned int ns = 0;
#pragma unroll
        for (int j = 0; j < 8; j++){
          if (stale & (1u << j)){
            unsigned int bad = ((gr[j].x ^ expv) | (gr[j].y ^ expv)
                              | (gr[j].z ^ expv) | (gr[j].w ^ expv)) & 0x00010001u;
            ns |= (bad ? 1u : 0u) << j;
          }
        }
        stale = ns;
      }
    }

    // ---- commit h/c to LDS. gr = [h01,c01,h23,c23] -> h {x,z}, c {y,w}
    {
#pragma unroll
      for (int j = 0; j < 8; j++){
        int row = wave * 4 + (j >> 1);
        int gg  = (j & 1) * 64 + lane;
        *(uint2*)(L + H_S + row * HSTR + gg * 8) = uint2{gr[j].x, gr[j].z};
        *(uint2*)(L + C_S + row * HSTR + gg * 8) = uint2{gr[j].y, gr[j].w};
      }
    }
    __syncthreads();   // B1: H/C committed (all waves past xproj reads of X)

    // ---- U-GEMM + decomp MFMA (Z 0..9); then stage X(t+1) (hides in MFMA)
    {
      f32x4 zA = {0.f,0.f,0.f,0.f}, zB = zA, zD = zA;
#pragma unroll
      for (int kc = 0; kc < 16; kc++){
        bf16x8 a = *(const bf16x8*)(L + H_S + lo * HSTR + kc*64 + hi*16);
        zA = MFMA(a, bP[kc], zA);
        zB = MFMA(a, bQ[kc], zB);
      }
      if (wave >= 2){
#pragma unroll
        for (int kc = 0; kc < 16; kc++){
          bf16x8 a = *(const bf16x8*)(L + C_S + lo * HSTR + kc*64 + hi*16);
          zD = MFMA(a, bR[kc], zD);
        }
      }
      zstore(L, g0*2+nt, lane, zA);
      zstore(L, g1*2+nt, lane, zB);
      if (wave >= 2) zstore(L, 8+nt, lane, zD);
    }
    if (t < T_STEPS - 1){
      char* dst = L + X_S + srow * XSTR + sseg * 32;
#pragma unroll
      for (int j = 0; j < 2; j++){
        float4 a = xv[2*j], b = xv[2*j+1];
        bf16x8 o = { (__bf16)a.x,(__bf16)a.y,(__bf16)a.z,(__bf16)a.w,
                     (__bf16)b.x,(__bf16)b.y,(__bf16)b.z,(__bf16)b.w };
        *(bf16x8*)(dst + j*16) = o;
      }
    }
    __syncthreads();   // B2: Z ready + X(t+1) staged

    // ---- elementwise gate math (fp32); publish tagged u64
    {
      float Tmap = 1.f / __logf(tv + 2.7183f);
      unsigned int hpk = 0, cpk = 0;
      float hv2[2];
#pragma unroll
      for (int e = 0; e < 2; e++){
        int col = ecp + e;
        int ntc = col >> 4, cl = col & 15;
        float zi = zread(L, 0+ntc,  erow, cl) + z2read(L, p2, 0+ntc, erow, cl) + bias_i[e];
        float zf = zread(L, 2+ntc,  erow, cl) + z2read(L, p2, 2+ntc, erow, cl) + bias_f[e];
        float zo = zread(L, 4+ntc,  erow, cl) + z2read(L, p2, 4+ntc, erow, cl) + bias_o[e];
        float zc = zread(L, 6+ntc,  erow, cl) + z2read(L, p2, 6+ntc, erow, cl) + bias_c[e];
        float zdv = zread(L, 8+ntc, erow, cl) + bias_d[e];
        float cst = ftanh(zdv);
        float c1  = cr[e] - cst + Tmap * cst;
        float ig = fsigm(zi), fg = fsigm(zf), og = fsigm(zo);
        float ch = ftanh(zc);
        float c2 = fg * c1 + ig * ch;
        float hv_ = og * ftanh(c2);
        cr[e] = c2; hv2[e] = hv_;
        hpk |= (unsigned int)__builtin_bit_cast(unsigned short, (__bf16)hv_) << (16*e);
        cpk |= (unsigned int)__builtin_bit_cast(unsigned short, (__bf16)c2) << (16*e);
      }
      if (t < T_STEPS - 1){
        const unsigned int wtag  = (unsigned int)((t + 1) & 3);
        const unsigned int tmask = (wtag & 1u) | ((wtag >> 1) << 16);
        hpk = (hpk & 0xFFFEFFFEu) | tmask;   // full tag in both bf16 LSBs
        cpk = (cpk & 0xFFFEFFFEu) | tmask;
        cst8(hcnext + pub_off,
             (unsigned long long)hpk | ((unsigned long long)cpk << 32));
      } else {
        size_t off = (size_t)(rbase + erow) * HID + cbase + ecp;
        P.h_final[off]     = hv2[0];
        P.h_final[off + 1] = hv2[1];
      }
    }
    // no tail barrier: next step's Z2 writes use opposite parity; next step's
    // commit (H/C writes) is after B1-crossing of all waves; X writes at
    // t+1's UGEMM phase are after B1(t+1). EW(t) reads are all pre-B1(t+1).
  }
}

// ---------------- head: out = relu(hT @ fc_w^T + fc_b) @ cls_w^T + cls_b ----
__global__ void __launch_bounds__(256) tlstm_head(const float* __restrict__ hfin,
    const float* __restrict__ fc_w, const float* __restrict__ fc_b,
    const float* __restrict__ cls_w, const float* __restrict__ cls_b,
    float* __restrict__ out)
{
  __shared__ float hrow[512];
  __shared__ float fcv[256];
  const int b = blockIdx.x, tid = threadIdx.x;
  ((float2*)hrow)[tid] = ((const float2*)(hfin + (size_t)b * 512))[tid];
  __syncthreads();
  {
    const float4* w4 = (const float4*)(fc_w + (size_t)tid * 512);
    const float4* h4 = (const float4*)hrow;
    float acc = fc_b[tid];
#pragma unroll 4
    for (int k = 0; k < 128; k++){
      float4 w = w4[k], h = h4[k];
      acc += w.x*h.x + w.y*h.y + w.z*h.z + w.w*h.w;
    }
    fcv[tid] = fmaxf(acc, 0.f);
  }
  __syncthreads();
  const int wave = tid >> 6, lane = tid & 63;
  if (wave < 2){
    const float* cw = cls_w + wave * 256;
    float s = 0.f;
#pragma unroll
    for (int j = lane; j < 256; j += 64) s += fcv[j] * cw[j];
#pragma unroll
    for (int off = 32; off > 0; off >>= 1) s += __shfl_down(s, off, 64);
    if (lane == 0) out[b * 2 + wave] = s + cls_b[wave];
  }
}

// ---------------------------------------------------------------------------
extern "C" void kernel_launch(void* const* d_in, const int* in_sizes, int n_in,
                              void* d_out, int out_size, void* d_ws, size_t ws_size,
                              hipStream_t stream)
{
  (void)in_sizes; (void)n_in; (void)out_size; (void)ws_size;

  ScanP P;
  P.x    = (const float*)d_in[0];
  P.tim  = (const float*)d_in[1];
  P.Wi_w = (const float*)d_in[2];  P.Wi_b = (const float*)d_in[3];
  P.Ui_w = (const float*)d_in[4];  P.Ui_b = (const float*)d_in[5];  P.bi  = (const float*)d_in[6];
  P.Wf_w = (const float*)d_in[7];  P.Wf_b = (const float*)d_in[8];
  P.Uf_w = (const float*)d_in[9];  P.Uf_b = (const float*)d_in[10]; P.bf_ = (const float*)d_in[11];
  P.Wo_w = (const float*)d_in[12]; P.Wo_b = (const float*)d_in[13];
  P.Uo_w = (const float*)d_in[14]; P.Uo_b = (const float*)d_in[15]; P.bo  = (const float*)d_in[16];
  P.Wc_w = (const float*)d_in[17]; P.Wc_b = (const float*)d_in[18];
  P.Uc_w = (const float*)d_in[19]; P.Uc_b = (const float*)d_in[20]; P.bc  = (const float*)d_in[21];
  P.Wd_w = (const float*)d_in[22]; P.b_dec = (const float*)d_in[23];
  const float* fc_w  = (const float*)d_in[24];
  const float* fc_b  = (const float*)d_in[25];
  const float* cls_w = (const float*)d_in[26];
  const float* cls_b = (const float*)d_in[27];

  // workspace layout (identical to R3..R15): [hc_buf 1M][flags 1K][h_final 512K]
  unsigned long long* hc_buf = (unsigned long long*)d_ws;        // 2*256*256 u64
  unsigned int* flags = (unsigned int*)(hc_buf + 2 * BATCH * 256);
  float* h_final = (float*)((char*)flags + 1024);                // 256*512 f32
  P.hc_buf = hc_buf; P.h_final = h_final; P.flags = flags;

  const size_t zero_bytes = (size_t)2 * BATCH * 256 * 8 + 1024;  // hc + flags
  hipMemsetAsync(d_ws, 0, zero_bytes, stream);

  hipLaunchKernelGGL(tlstm_scan, dim3(256), dim3(256), 0, stream, P);
  hipLaunchKernelGGL(tlstm_head, dim3(256), dim3(256), 0, stream,
                     h_final, fc_w, fc_b, cls_w, cls_b, (float*)d_out);
}